// Round 9
// baseline (716.683 us; speedup 1.0000x reference)
//
#include <hip/hip_runtime.h>

#define H96 96
#define LAYERS 6
#define BN_EPS 1e-5f
#define SCAN_B 1024

typedef unsigned short u16;
typedef unsigned int u32;
typedef _Float16 f16;
typedef _Float16 h8 __attribute__((ext_vector_type(8)));
typedef float f32x4 __attribute__((ext_vector_type(4)));

__device__ __forceinline__ float sigm(float x) { return 1.f / (1.f + __expf(-x)); }
__device__ __forceinline__ float tanh_(float x) { return 2.f / (1.f + __expf(-2.f * x)) - 1.f; }
__device__ __forceinline__ f32x4 splat4(float x) { f32x4 v = {x, x, x, x}; return v; }

struct h2s { f16 x, y; };

__device__ __forceinline__ void macc(float* acc, h8 v, float m) {
#pragma unroll
    for (int j = 0; j < 8; j++) acc[j] += (float)v[j] * m;
}

// ---------- weight f32 -> f16 conversion ----------
__global__ void k_f2h(const float* __restrict__ convw, const float* __restrict__ wih,
                      const float* __restrict__ whh, const float* __restrict__ fc1w,
                      const float* __restrict__ fc2w, f16* __restrict__ dst) {
    int i = blockIdx.x * 256 + threadIdx.x;
    if (i >= 184320) return;
    float v;
    if (i < 55296) v = convw[i];
    else if (i < 82944) v = wih[i - 55296];
    else if (i < 110592) v = whh[i - 82944];
    else if (i < 147456) v = fc1w[i - 110592];
    else v = fc2w[i - 147456];
    dst[i] = (f16)v;
}

// ---------- WpT[l][j][k] = sum_m w_ih[j][m] * conv_w[l][k][m]  (j<288, k<96) ----------
__global__ __launch_bounds__(256) void k_wpt(const f16* __restrict__ wih16, const f16* __restrict__ convw16,
                                             f16* __restrict__ wpt) {
    int l = blockIdx.y;
    int lane = threadIdx.x & 63, wave = threadIdx.x >> 6;
    int l15 = lane & 15, q = lane >> 4;
    int rowa = blockIdx.x * 64 + wave * 16 + l15;
    if (rowa >= 288) rowa = 287;
    const f16* B = convw16 + (size_t)l * 9216;
    h8 af[3];
#pragma unroll
    for (int s = 0; s < 3; s++) af[s] = *(const h8*)(wih16 + (size_t)rowa * 96 + s * 32 + q * 8);
    f32x4 acc[6];
#pragma unroll
    for (int t = 0; t < 6; t++) acc[t] = splat4(0.f);
#pragma unroll
    for (int s = 0; s < 3; s++)
#pragma unroll
        for (int t = 0; t < 6; t++) {
            h8 b = *(const h8*)(B + (size_t)(t * 16 + l15) * 96 + s * 32 + q * 8);
            acc[t] = __builtin_amdgcn_mfma_f32_16x16x32_f16(af[s], b, acc[t], 0, 0, 0);
        }
    int rbase = blockIdx.x * 64 + wave * 16 + q * 4;
#pragma unroll
    for (int t = 0; t < 6; t++)
#pragma unroll
        for (int rr = 0; rr < 4; rr++) {
            int row = rbase + rr;
            if (row < 288) wpt[(size_t)l * 27648 + (size_t)row * 96 + t * 16 + l15] = (f16)acc[t][rr];
        }
}

// ---------- pad ----------
__global__ void k_pad(const float* __restrict__ x, f16* __restrict__ hf, int N) {
    int i = blockIdx.x * 256 + threadIdx.x;
    if (i >= N * H96) return;
    int n = i / H96, c = i - n * H96;
    float v = (c < 32) ? x[n * 32 + c] : 0.f;
    hf[i] = (f16)v;
}

// ---------- CSR build ----------
__global__ void k_hist(const int* __restrict__ key, int* __restrict__ deg, int E) {
    int e = blockIdx.x * 256 + threadIdx.x;
    if (e < E) atomicAdd(&deg[key[e]], 1);
}

__global__ __launch_bounds__(SCAN_B) void k_scan1(const int* __restrict__ deg, int* __restrict__ incl,
                                                  int* __restrict__ bsum, int N) {
    __shared__ int sh[SCAN_B];
    int i = blockIdx.x * SCAN_B + threadIdx.x;
    int v = (i < N) ? deg[i] : 0;
    sh[threadIdx.x] = v;
    __syncthreads();
    for (int off = 1; off < SCAN_B; off <<= 1) {
        int t = (threadIdx.x >= (u32)off) ? sh[threadIdx.x - off] : 0;
        __syncthreads();
        sh[threadIdx.x] += t;
        __syncthreads();
    }
    incl[blockIdx.x * SCAN_B + threadIdx.x] = sh[threadIdx.x];
    if (threadIdx.x == SCAN_B - 1) bsum[blockIdx.x] = sh[threadIdx.x];
}

__global__ void k_scan2(int* __restrict__ bsum, int nb) {
    if (blockIdx.x == 0 && threadIdx.x == 0) {
        int run = 0;
        for (int i = 0; i < nb; i++) { run += bsum[i]; bsum[i] = run; }
    }
}

__global__ void k_scan3(const int* __restrict__ deg, const int* __restrict__ incl, const int* __restrict__ bsum,
                        int* __restrict__ rs, int* __restrict__ cur, int N, int E) {
    int i = blockIdx.x * 256 + threadIdx.x;
    if (i == 0) rs[N] = E;
    if (i < N) {
        int b = i / SCAN_B;
        int off = (b > 0) ? bsum[b - 1] : 0;
        int ex = incl[i] - deg[i] + off;
        rs[i] = ex;
        if (cur) cur[i] = ex;
    }
}

__global__ void k_fill(const int* __restrict__ src, const int* __restrict__ dst, int* __restrict__ cur,
                       int* __restrict__ es, int E) {
    int e = blockIdx.x * 256 + threadIdx.x;
    if (e < E) {
        int p = atomicAdd(&cur[dst[e]], 1);
        es[p] = src[e];
    }
}

// ---------- fused layer: per-wave gather (into A-frag registers) + GRU ----------
// One wave owns 16 rows. Lane (l15,q): gathers agg[base+l15][s*32+q*8..+8] over the
// row's edge chain (f32 acc, predicated 4-wide batches), packs to f16 A-frags,
// then computes all 6 gate-column tiles. NO barriers, NO LDS -> waves in gather
// phase co-schedule with waves in MFMA phase on the same CU.
__global__ __launch_bounds__(256) void k_layer(const f16* __restrict__ hin, f16* __restrict__ hout,
                                               const int* __restrict__ rs, const int* __restrict__ es,
                                               const f16* __restrict__ wpt, const f16* __restrict__ whh,
                                               const float* __restrict__ bih, const float* __restrict__ bhh,
                                               int N) {
    int wave = threadIdx.x >> 6;
    int lane = threadIdx.x & 63;
    int l15 = lane & 15, q = lane >> 4;
    int base = (blockIdx.x * 4 + wave) << 4;
    if (base >= N) return;
    int row = base + l15;
    if (row >= N) row = N - 1;

    // ---- gather phase ----
    float acc[24];
#pragma unroll
    for (int j = 0; j < 24; j++) acc[j] = 0.f;
    {
        int s0 = rs[row], e0 = rs[row + 1];
        const char* basep = (const char*)hin;
        int off = q * 16;  // byte offset of this lane's 8-col chunk within each 64-B s-block
        for (int i = s0; i < e0; i += 4) {
            int j1 = (i + 1 < e0) ? i + 1 : i;
            int j2 = (i + 2 < e0) ? i + 2 : i;
            int j3 = (i + 3 < e0) ? i + 3 : i;
            float m1 = (i + 1 < e0) ? 1.f : 0.f;
            float m2 = (i + 2 < e0) ? 1.f : 0.f;
            float m3 = (i + 3 < e0) ? 1.f : 0.f;
            const char* pa = basep + (size_t)es[i] * 192 + off;
            const char* pb = basep + (size_t)es[j1] * 192 + off;
            const char* pc = basep + (size_t)es[j2] * 192 + off;
            const char* pd = basep + (size_t)es[j3] * 192 + off;
#pragma unroll
            for (int s = 0; s < 3; s++) {
                h8 va = *(const h8*)(pa + s * 64);
                h8 vb = *(const h8*)(pb + s * 64);
                h8 vc = *(const h8*)(pc + s * 64);
                h8 vd = *(const h8*)(pd + s * 64);
                macc(acc + s * 8, va, 1.f);
                macc(acc + s * 8, vb, m1);
                macc(acc + s * 8, vc, m2);
                macc(acc + s * 8, vd, m3);
            }
        }
    }
    // pack agg to f16 A-frags; load own-h A-frags
    h8 as_[3], ah[3];
#pragma unroll
    for (int s = 0; s < 3; s++) {
        h8 t;
#pragma unroll
        for (int j = 0; j < 8; j++) t[j] = (f16)acc[s * 8 + j];
        as_[s] = t;
        ah[s] = *(const h8*)(hin + (size_t)row * H96 + s * 32 + q * 8);
    }

    // ---- GRU phase: 6 gate-column tiles ----
#pragma unroll
    for (int t = 0; t < 6; t++) {
        int jr = t * 16 + l15;
        f32x4 r = splat4(bih[jr] + bhh[jr]);
        f32x4 z = splat4(bih[96 + jr] + bhh[96 + jr]);
        f32x4 nn = splat4(bih[192 + jr]);
        f32x4 hn = splat4(bhh[192 + jr]);
#pragma unroll
        for (int s = 0; s < 3; s++) {
            int ko = s * 32 + q * 8;
            h8 wr0 = *(const h8*)(wpt + (size_t)jr * H96 + ko);
            h8 wr1 = *(const h8*)(whh + (size_t)jr * H96 + ko);
            h8 wz0 = *(const h8*)(wpt + (size_t)(96 + jr) * H96 + ko);
            h8 wz1 = *(const h8*)(whh + (size_t)(96 + jr) * H96 + ko);
            h8 wn0 = *(const h8*)(wpt + (size_t)(192 + jr) * H96 + ko);
            h8 wn1 = *(const h8*)(whh + (size_t)(192 + jr) * H96 + ko);
            r = __builtin_amdgcn_mfma_f32_16x16x32_f16(as_[s], wr0, r, 0, 0, 0);
            r = __builtin_amdgcn_mfma_f32_16x16x32_f16(ah[s], wr1, r, 0, 0, 0);
            z = __builtin_amdgcn_mfma_f32_16x16x32_f16(as_[s], wz0, z, 0, 0, 0);
            z = __builtin_amdgcn_mfma_f32_16x16x32_f16(ah[s], wz1, z, 0, 0, 0);
            nn = __builtin_amdgcn_mfma_f32_16x16x32_f16(as_[s], wn0, nn, 0, 0, 0);
            hn = __builtin_amdgcn_mfma_f32_16x16x32_f16(ah[s], wn1, hn, 0, 0, 0);
        }
        int rbase = base + q * 4;
#pragma unroll
        for (int rr = 0; rr < 4; rr++) {
            int row2 = rbase + rr;
            if (row2 < N) {
                float rv = sigm(r[rr]);
                float zv = sigm(z[rr]);
                float nv = tanh_(nn[rr] + rv * hn[rr]);
                size_t idx = (size_t)row2 * H96 + t * 16 + l15;
                float hold = (float)hin[idx];
                float hnew = (1.f - zv) * nv + zv * hold;
                hout[idx] = (f16)hnew;
            }
        }
    }
}

// ---------- fused pool + BN ----------
__global__ void k_pool2(const f16* __restrict__ hf, const int* __restrict__ grs,
                        const float* __restrict__ gamma, const float* __restrict__ beta,
                        f16* __restrict__ pooled, int Gn) {
    int g = blockIdx.x;
    int c = threadIdx.x;
    if (g >= Gn || c >= H96) return;
    int s = grs[g], e = grs[g + 1];
    float sum = 0.f;
    for (int n = s; n < e; n++) sum += fmaxf((float)hf[(size_t)n * H96 + c], 0.f);
    float cnt = fmaxf((float)(e - s), 1.f);
    float val = (sum / cnt) * (gamma[c] * rsqrtf(1.f + BN_EPS)) + beta[c];
    pooled[(size_t)g * H96 + c] = (f16)val;
}

// ---------- MLP GEMM ----------
template <int KS, int NT, bool RELU>
__global__ __launch_bounds__(256) void k_mlp(const f16* __restrict__ A, const f16* __restrict__ W,
                                             const float* __restrict__ bias, f16* __restrict__ out, int M) {
    int lane = threadIdx.x & 63, wave = threadIdx.x >> 6;
    int l15 = lane & 15, q = lane >> 4;
    int tile = blockIdx.x;
    int rowa = tile * 64 + wave * 16 + l15;
    if (rowa >= M) rowa = M - 1;
    h8 af[KS];
#pragma unroll
    for (int s = 0; s < KS; s++) af[s] = *(const h8*)(A + (size_t)rowa * (KS * 32) + s * 32 + q * 8);
    f32x4 acc[NT];
#pragma unroll
    for (int t = 0; t < NT; t++) acc[t] = splat4(0.f);
#pragma unroll
    for (int s = 0; s < KS; s++)
#pragma unroll
        for (int t = 0; t < NT; t++) {
            h8 b = *(const h8*)(W + (size_t)(t * 16 + l15) * (KS * 32) + s * 32 + q * 8);
            acc[t] = __builtin_amdgcn_mfma_f32_16x16x32_f16(af[s], b, acc[t], 0, 0, 0);
        }
    int rbase = tile * 64 + wave * 16 + q * 4;
#pragma unroll
    for (int t = 0; t < NT; t++) {
        float bv = bias[t * 16 + l15];
#pragma unroll
        for (int rr = 0; rr < 4; rr++) {
            int row = rbase + rr;
            if (row >= M) continue;
            float v = acc[t][rr] + bv;
            if (RELU) v = fmaxf(v, 0.f);
            out[(size_t)row * (NT * 16) + t * 16 + l15] = (f16)v;
        }
    }
}

__global__ void k_mlp3(const f16* __restrict__ h2, const float* __restrict__ w, const float* __restrict__ b,
                       float* __restrict__ out, int M) {
    int g = blockIdx.x * 256 + threadIdx.x;
    if (g >= M) return;
    float acc = 0.f;
    for (int k = 0; k < H96; k++) acc += (float)h2[(size_t)g * H96 + k] * w[k];
    out[g] = acc + b[0];
}

extern "C" void kernel_launch(void* const* d_in, const int* in_sizes, int n_in, void* d_out, int out_size,
                              void* d_ws, size_t ws_size, hipStream_t stream) {
    const float* x = (const float*)d_in[0];
    const int* ei = (const int*)d_in[1];
    const int* batch = (const int*)d_in[2];
    const float* conv_w = (const float*)d_in[3];
    const float* wih = (const float*)d_in[4];
    const float* whh = (const float*)d_in[5];
    const float* bih = (const float*)d_in[6];
    const float* bhh = (const float*)d_in[7];
    const float* gamma = (const float*)d_in[8];
    const float* beta = (const float*)d_in[9];
    const float* fc1w = (const float*)d_in[10];
    const float* fc1b = (const float*)d_in[11];
    const float* fc2w = (const float*)d_in[12];
    const float* fc2b = (const float*)d_in[13];
    const float* fc3w = (const float*)d_in[14];
    const float* fc3b = (const float*)d_in[15];

    int N = in_sizes[0] / 32;
    int E = in_sizes[1] / 2;
    int Gn = out_size;  // 4096
    const int* srcp = ei;
    const int* dstp = ei + E;

    char* p = (char*)d_ws;
    auto alloc = [&](size_t bytes) -> char* {
        char* r = p;
        p += (bytes + 255) & ~(size_t)255;
        return r;
    };
    f16* hA = (f16*)alloc((size_t)N * H96 * 2);
    f16* hB = (f16*)alloc((size_t)N * H96 * 2);
    f16* wf16 = (f16*)alloc((size_t)184320 * 2);
    f16* wpt = (f16*)alloc((size_t)LAYERS * 27648 * 2);
    int nb = (N + SCAN_B - 1) / SCAN_B;
    int* deg = (int*)alloc((size_t)N * 4);
    int* incl = (int*)alloc((size_t)nb * SCAN_B * 4);
    int* bsum = (int*)alloc((size_t)nb * 4);
    int* rs = (int*)alloc((size_t)(N + 1) * 4);
    int* cur = (int*)alloc((size_t)N * 4);
    int* es = (int*)alloc((size_t)E * 4);
    int nb2 = (Gn + SCAN_B - 1) / SCAN_B;
    int* gdeg = (int*)alloc((size_t)Gn * 4);
    int* gincl = (int*)alloc((size_t)nb2 * SCAN_B * 4);
    int* gbsum = (int*)alloc((size_t)nb2 * 4);
    int* grs = (int*)alloc((size_t)(Gn + 1) * 4);
    f16* pooled = (f16*)alloc((size_t)Gn * H96 * 2);
    f16* h1 = (f16*)alloc((size_t)Gn * 384 * 2);
    f16* h2 = (f16*)alloc((size_t)Gn * H96 * 2);

    f16* convw16 = wf16;
    f16* wih16 = wf16 + 55296;
    f16* whh16 = wf16 + 82944;
    f16* fc1w16 = wf16 + 110592;
    f16* fc2w16 = wf16 + 147456;

    hipMemsetAsync(deg, 0, (size_t)N * 4, stream);
    hipMemsetAsync(gdeg, 0, (size_t)Gn * 4, stream);

    k_f2h<<<720, 256, 0, stream>>>(conv_w, wih, whh, fc1w, fc2w, wf16);
    k_wpt<<<dim3(5, 6), 256, 0, stream>>>(wih16, convw16, wpt);
    k_pad<<<(N * H96 + 255) / 256, 256, 0, stream>>>(x, hA, N);
    // edge CSR (by dst)
    k_hist<<<(E + 255) / 256, 256, 0, stream>>>(dstp, deg, E);
    k_scan1<<<nb, SCAN_B, 0, stream>>>(deg, incl, bsum, N);
    k_scan2<<<1, 64, 0, stream>>>(bsum, nb);
    k_scan3<<<(N + 255) / 256, 256, 0, stream>>>(deg, incl, bsum, rs, cur, N, E);
    k_fill<<<(E + 255) / 256, 256, 0, stream>>>(srcp, dstp, cur, es, E);
    // graph CSR (batch sorted)
    k_hist<<<(N + 255) / 256, 256, 0, stream>>>(batch, gdeg, N);
    k_scan1<<<nb2, SCAN_B, 0, stream>>>(gdeg, gincl, gbsum, Gn);
    k_scan2<<<1, 64, 0, stream>>>(gbsum, nb2);
    k_scan3<<<(Gn + 255) / 256, 256, 0, stream>>>(gdeg, gincl, gbsum, grs, (int*)nullptr, Gn, N);

    int nblk = (N + 63) / 64;  // 4 waves/block, 16 rows/wave
    for (int l = 0; l < LAYERS; l++) {
        f16* hin = (l & 1) ? hB : hA;
        f16* hout = (l & 1) ? hA : hB;
        k_layer<<<nblk, 256, 0, stream>>>(hin, hout, rs, es, wpt + (size_t)l * 27648, whh16, bih, bhh, N);
    }

    k_pool2<<<Gn, 128, 0, stream>>>(hA, grs, gamma, beta, pooled, Gn);
    k_mlp<3, 24, true><<<(Gn + 63) / 64, 256, 0, stream>>>(pooled, fc1w16, fc1b, h1, Gn);
    k_mlp<12, 6, true><<<(Gn + 63) / 64, 256, 0, stream>>>(h1, fc2w16, fc2b, h2, Gn);
    k_mlp3<<<(Gn + 255) / 256, 256, 0, stream>>>(h2, fc3w, fc3b, (float*)d_out, Gn);
}

// Round 10
// 558.138 us; speedup vs baseline: 1.2841x; 1.2841x over previous
//
#include <hip/hip_runtime.h>

#define H96 96
#define LAYERS 6
#define BN_EPS 1e-5f
#define SCAN_B 1024

typedef unsigned short u16;
typedef unsigned int u32;
typedef _Float16 f16;
typedef _Float16 h8 __attribute__((ext_vector_type(8)));
typedef float f32x4 __attribute__((ext_vector_type(4)));
typedef u32 u32x3 __attribute__((ext_vector_type(3)));

__device__ __forceinline__ float sigm(float x) { return 1.f / (1.f + __expf(-x)); }
__device__ __forceinline__ float tanh_(float x) { return 2.f / (1.f + __expf(-2.f * x)) - 1.f; }
__device__ __forceinline__ f32x4 splat4(float x) { f32x4 v = {x, x, x, x}; return v; }

struct h2s { f16 x, y; };

// unpack one dword (two f16) into two floats, by value
__device__ __forceinline__ void upk(u32 v, float& lo, float& hi) {
    union { u32 u; h2s h; } c;
    c.u = v;
    lo = (float)c.h.x;
    hi = (float)c.h.y;
}

// ---------- weight f32 -> f16 conversion ----------
__global__ void k_f2h(const float* __restrict__ convw, const float* __restrict__ wih,
                      const float* __restrict__ whh, const float* __restrict__ fc1w,
                      const float* __restrict__ fc2w, f16* __restrict__ dst) {
    int i = blockIdx.x * 256 + threadIdx.x;
    if (i >= 184320) return;
    float v;
    if (i < 55296) v = convw[i];
    else if (i < 82944) v = wih[i - 55296];
    else if (i < 110592) v = whh[i - 82944];
    else if (i < 147456) v = fc1w[i - 110592];
    else v = fc2w[i - 147456];
    dst[i] = (f16)v;
}

// ---------- WpT[l][j][k] = sum_m w_ih[j][m] * conv_w[l][k][m]  (j<288, k<96) ----------
__global__ __launch_bounds__(256) void k_wpt(const f16* __restrict__ wih16, const f16* __restrict__ convw16,
                                             f16* __restrict__ wpt) {
    int l = blockIdx.y;
    int lane = threadIdx.x & 63, wave = threadIdx.x >> 6;
    int l15 = lane & 15, q = lane >> 4;
    int rowa = blockIdx.x * 64 + wave * 16 + l15;
    if (rowa >= 288) rowa = 287;
    const f16* B = convw16 + (size_t)l * 9216;
    h8 af[3];
#pragma unroll
    for (int s = 0; s < 3; s++) af[s] = *(const h8*)(wih16 + (size_t)rowa * 96 + s * 32 + q * 8);
    f32x4 acc[6];
#pragma unroll
    for (int t = 0; t < 6; t++) acc[t] = splat4(0.f);
#pragma unroll
    for (int s = 0; s < 3; s++)
#pragma unroll
        for (int t = 0; t < 6; t++) {
            h8 b = *(const h8*)(B + (size_t)(t * 16 + l15) * 96 + s * 32 + q * 8);
            acc[t] = __builtin_amdgcn_mfma_f32_16x16x32_f16(af[s], b, acc[t], 0, 0, 0);
        }
    int rbase = blockIdx.x * 64 + wave * 16 + q * 4;
#pragma unroll
    for (int t = 0; t < 6; t++)
#pragma unroll
        for (int rr = 0; rr < 4; rr++) {
            int row = rbase + rr;
            if (row < 288) wpt[(size_t)l * 27648 + (size_t)row * 96 + t * 16 + l15] = (f16)acc[t][rr];
        }
}

// ---------- pad ----------
__global__ void k_pad(const float* __restrict__ x, f16* __restrict__ hf, int N) {
    int i = blockIdx.x * 256 + threadIdx.x;
    if (i >= N * H96) return;
    int n = i / H96, c = i - n * H96;
    float v = (c < 32) ? x[n * 32 + c] : 0.f;
    hf[i] = (f16)v;
}

// ---------- CSR build ----------
__global__ void k_hist(const int* __restrict__ key, int* __restrict__ deg, int E) {
    int e = blockIdx.x * 256 + threadIdx.x;
    if (e < E) atomicAdd(&deg[key[e]], 1);
}

__global__ __launch_bounds__(SCAN_B) void k_scan1(const int* __restrict__ deg, int* __restrict__ incl,
                                                  int* __restrict__ bsum, int N) {
    __shared__ int sh[SCAN_B];
    int i = blockIdx.x * SCAN_B + threadIdx.x;
    int v = (i < N) ? deg[i] : 0;
    sh[threadIdx.x] = v;
    __syncthreads();
    for (int off = 1; off < SCAN_B; off <<= 1) {
        int t = (threadIdx.x >= (u32)off) ? sh[threadIdx.x - off] : 0;
        __syncthreads();
        sh[threadIdx.x] += t;
        __syncthreads();
    }
    incl[blockIdx.x * SCAN_B + threadIdx.x] = sh[threadIdx.x];
    if (threadIdx.x == SCAN_B - 1) bsum[blockIdx.x] = sh[threadIdx.x];
}

__global__ void k_scan2(int* __restrict__ bsum, int nb) {
    if (blockIdx.x == 0 && threadIdx.x == 0) {
        int run = 0;
        for (int i = 0; i < nb; i++) { run += bsum[i]; bsum[i] = run; }
    }
}

__global__ void k_scan3(const int* __restrict__ deg, const int* __restrict__ incl, const int* __restrict__ bsum,
                        int* __restrict__ rs, int* __restrict__ cur, int N, int E) {
    int i = blockIdx.x * 256 + threadIdx.x;
    if (i == 0) rs[N] = E;
    if (i < N) {
        int b = i / SCAN_B;
        int off = (b > 0) ? bsum[b - 1] : 0;
        int ex = incl[i] - deg[i] + off;
        rs[i] = ex;
        if (cur) cur[i] = ex;
    }
}

__global__ void k_fill(const int* __restrict__ src, const int* __restrict__ dst, int* __restrict__ cur,
                       int* __restrict__ es, int E) {
    int e = blockIdx.x * 256 + threadIdx.x;
    if (e < E) {
        int p = atomicAdd(&cur[dst[e]], 1);
        es[p] = src[e];
    }
}

// ---------- gather: agg[n] = sum_{e in in(n)} h[src_e] ----------
// 16 nodes/block; 16-lane group per node, lane covers 6 cols (one dwordx3 per edge).
// Flat predicated 4-wide loop: always 4 clamped loads in flight, masked accumulate.
__global__ __launch_bounds__(256) void k_gather(const f16* __restrict__ hin, const int* __restrict__ rs,
                                                const int* __restrict__ es, f16* __restrict__ agg, int N) {
    int grp = threadIdx.x >> 4;
    int lane6 = threadIdx.x & 15;
    int node = blockIdx.x * 16 + grp;
    if (node >= N) return;
    int s = rs[node], e = rs[node + 1];
    float a0 = 0, a1 = 0, a2 = 0, a3 = 0, a4 = 0, a5 = 0;
    const char* basep = (const char*)hin;
    int off = lane6 * 12;
    for (int i = s; i < e; i += 4) {
        int j1 = (i + 1 < e) ? i + 1 : i;
        int j2 = (i + 2 < e) ? i + 2 : i;
        int j3 = (i + 3 < e) ? i + 3 : i;
        float m1 = (i + 1 < e) ? 1.f : 0.f;
        float m2 = (i + 2 < e) ? 1.f : 0.f;
        float m3 = (i + 3 < e) ? 1.f : 0.f;
        int sa = es[i], sb = es[j1], sc = es[j2], sd = es[j3];
        u32x3 va = *(const u32x3*)(basep + (size_t)sa * 192 + off);
        u32x3 vb = *(const u32x3*)(basep + (size_t)sb * 192 + off);
        u32x3 vc = *(const u32x3*)(basep + (size_t)sc * 192 + off);
        u32x3 vd = *(const u32x3*)(basep + (size_t)sd * 192 + off);
        float t0, t1;
        upk(va.x, t0, t1); a0 += t0; a1 += t1;
        upk(va.y, t0, t1); a2 += t0; a3 += t1;
        upk(va.z, t0, t1); a4 += t0; a5 += t1;
        upk(vb.x, t0, t1); a0 += t0 * m1; a1 += t1 * m1;
        upk(vb.y, t0, t1); a2 += t0 * m1; a3 += t1 * m1;
        upk(vb.z, t0, t1); a4 += t0 * m1; a5 += t1 * m1;
        upk(vc.x, t0, t1); a0 += t0 * m2; a1 += t1 * m2;
        upk(vc.y, t0, t1); a2 += t0 * m2; a3 += t1 * m2;
        upk(vc.z, t0, t1); a4 += t0 * m2; a5 += t1 * m2;
        upk(vd.x, t0, t1); a0 += t0 * m3; a1 += t1 * m3;
        upk(vd.y, t0, t1); a2 += t0 * m3; a3 += t1 * m3;
        upk(vd.z, t0, t1); a4 += t0 * m3; a5 += t1 * m3;
    }
    f16* dp = agg + (size_t)node * H96 + lane6 * 6;
    h2s p0, p1, p2;
    p0.x = (f16)a0; p0.y = (f16)a1;
    p1.x = (f16)a2; p1.y = (f16)a3;
    p2.x = (f16)a4; p2.y = (f16)a5;
    *(h2s*)(dp + 0) = p0;
    *(h2s*)(dp + 2) = p1;
    *(h2s*)(dp + 4) = p2;
}

// ---------- GRU: r7 structure + VGPR budget 128 so hoisted weights actually persist ----------
// 6 waves/block, wave w owns output cols [16w,16w+16); grid-stride over 16-row tiles.
// __launch_bounds__(384,4): 4 waves/EU min -> <=128 VGPR -> 72 weight regs stay resident.
__global__ __launch_bounds__(384, 4) void k_gru(const f16* __restrict__ agg, const f16* __restrict__ hin,
                                                f16* __restrict__ hout, const f16* __restrict__ wpt,
                                                const f16* __restrict__ whh, const float* __restrict__ bih,
                                                const float* __restrict__ bhh, int N) {
    int w = threadIdx.x >> 6;
    int lane = threadIdx.x & 63;
    int l15 = lane & 15, q = lane >> 4;
    int jr = w * 16 + l15;
    float b_r = bih[jr] + bhh[jr];
    float b_z = bih[96 + jr] + bhh[96 + jr];
    float b_in = bih[192 + jr];
    float b_hn = bhh[192 + jr];
    h8 wr0[3], wr1[3], wz0[3], wz1[3], wn0[3], wn1[3];
#pragma unroll
    for (int s = 0; s < 3; s++) {
        int ko = s * 32 + q * 8;
        wr0[s] = *(const h8*)(wpt + (size_t)jr * H96 + ko);
        wz0[s] = *(const h8*)(wpt + (size_t)(96 + jr) * H96 + ko);
        wn0[s] = *(const h8*)(wpt + (size_t)(192 + jr) * H96 + ko);
        wr1[s] = *(const h8*)(whh + (size_t)jr * H96 + ko);
        wz1[s] = *(const h8*)(whh + (size_t)(96 + jr) * H96 + ko);
        wn1[s] = *(const h8*)(whh + (size_t)(192 + jr) * H96 + ko);
    }
    int ntiles = (N + 15) >> 4;
    for (int tile = blockIdx.x; tile < ntiles; tile += gridDim.x) {
        int base = tile << 4;
        int rowa = base + l15;
        if (rowa >= N) rowa = N - 1;
        h8 as_[3], ah[3];
#pragma unroll
        for (int s = 0; s < 3; s++) {
            as_[s] = *(const h8*)(agg + (size_t)rowa * H96 + s * 32 + q * 8);
            ah[s] = *(const h8*)(hin + (size_t)rowa * H96 + s * 32 + q * 8);
        }
        f32x4 r = splat4(b_r), z = splat4(b_z), nn = splat4(b_in), hn = splat4(b_hn);
#pragma unroll
        for (int s = 0; s < 3; s++) {
            r = __builtin_amdgcn_mfma_f32_16x16x32_f16(as_[s], wr0[s], r, 0, 0, 0);
            r = __builtin_amdgcn_mfma_f32_16x16x32_f16(ah[s], wr1[s], r, 0, 0, 0);
            z = __builtin_amdgcn_mfma_f32_16x16x32_f16(as_[s], wz0[s], z, 0, 0, 0);
            z = __builtin_amdgcn_mfma_f32_16x16x32_f16(ah[s], wz1[s], z, 0, 0, 0);
            nn = __builtin_amdgcn_mfma_f32_16x16x32_f16(as_[s], wn0[s], nn, 0, 0, 0);
            hn = __builtin_amdgcn_mfma_f32_16x16x32_f16(ah[s], wn1[s], hn, 0, 0, 0);
        }
        int rbase = base + q * 4;
#pragma unroll
        for (int rr = 0; rr < 4; rr++) {
            int row = rbase + rr;
            if (row < N) {
                float rv = sigm(r[rr]);
                float zv = sigm(z[rr]);
                float nv = tanh_(nn[rr] + rv * hn[rr]);
                size_t idx = (size_t)row * H96 + w * 16 + l15;
                float hold = (float)hin[idx];
                float hnew = (1.f - zv) * nv + zv * hold;
                hout[idx] = (f16)hnew;
            }
        }
    }
}

// ---------- fused pool + BN ----------
__global__ void k_pool2(const f16* __restrict__ hf, const int* __restrict__ grs,
                        const float* __restrict__ gamma, const float* __restrict__ beta,
                        f16* __restrict__ pooled, int Gn) {
    int g = blockIdx.x;
    int c = threadIdx.x;
    if (g >= Gn || c >= H96) return;
    int s = grs[g], e = grs[g + 1];
    float sum = 0.f;
    for (int n = s; n < e; n++) sum += fmaxf((float)hf[(size_t)n * H96 + c], 0.f);
    float cnt = fmaxf((float)(e - s), 1.f);
    float val = (sum / cnt) * (gamma[c] * rsqrtf(1.f + BN_EPS)) + beta[c];
    pooled[(size_t)g * H96 + c] = (f16)val;
}

// ---------- MLP GEMM: out = act(A @ W^T + b); blockIdx.y selects a column group ----------
template <int KS, int NT, int OUTW, bool RELU>
__global__ __launch_bounds__(256) void k_mlp(const f16* __restrict__ A, const f16* __restrict__ W,
                                             const float* __restrict__ bias, f16* __restrict__ out, int M) {
    int lane = threadIdx.x & 63, wave = threadIdx.x >> 6;
    int l15 = lane & 15, q = lane >> 4;
    int colBase = blockIdx.y * (NT * 16);
    int tile = blockIdx.x;
    int rowa = tile * 64 + wave * 16 + l15;
    if (rowa >= M) rowa = M - 1;
    h8 af[KS];
#pragma unroll
    for (int s = 0; s < KS; s++) af[s] = *(const h8*)(A + (size_t)rowa * (KS * 32) + s * 32 + q * 8);
    f32x4 acc[NT];
#pragma unroll
    for (int t = 0; t < NT; t++) acc[t] = splat4(0.f);
#pragma unroll
    for (int s = 0; s < KS; s++)
#pragma unroll
        for (int t = 0; t < NT; t++) {
            h8 b = *(const h8*)(W + (size_t)(colBase + t * 16 + l15) * (KS * 32) + s * 32 + q * 8);
            acc[t] = __builtin_amdgcn_mfma_f32_16x16x32_f16(af[s], b, acc[t], 0, 0, 0);
        }
    int rbase = tile * 64 + wave * 16 + q * 4;
#pragma unroll
    for (int t = 0; t < NT; t++) {
        float bv = bias[colBase + t * 16 + l15];
#pragma unroll
        for (int rr = 0; rr < 4; rr++) {
            int row = rbase + rr;
            if (row >= M) continue;
            float v = acc[t][rr] + bv;
            if (RELU) v = fmaxf(v, 0.f);
            out[(size_t)row * OUTW + colBase + t * 16 + l15] = (f16)v;
        }
    }
}

__global__ void k_mlp3(const f16* __restrict__ h2, const float* __restrict__ w, const float* __restrict__ b,
                       float* __restrict__ out, int M) {
    int g = blockIdx.x * 256 + threadIdx.x;
    if (g >= M) return;
    float acc = 0.f;
    for (int k = 0; k < H96; k++) acc += (float)h2[(size_t)g * H96 + k] * w[k];
    out[g] = acc + b[0];
}

extern "C" void kernel_launch(void* const* d_in, const int* in_sizes, int n_in, void* d_out, int out_size,
                              void* d_ws, size_t ws_size, hipStream_t stream) {
    const float* x = (const float*)d_in[0];
    const int* ei = (const int*)d_in[1];
    const int* batch = (const int*)d_in[2];
    const float* conv_w = (const float*)d_in[3];
    const float* wih = (const float*)d_in[4];
    const float* whh = (const float*)d_in[5];
    const float* bih = (const float*)d_in[6];
    const float* bhh = (const float*)d_in[7];
    const float* gamma = (const float*)d_in[8];
    const float* beta = (const float*)d_in[9];
    const float* fc1w = (const float*)d_in[10];
    const float* fc1b = (const float*)d_in[11];
    const float* fc2w = (const float*)d_in[12];
    const float* fc2b = (const float*)d_in[13];
    const float* fc3w = (const float*)d_in[14];
    const float* fc3b = (const float*)d_in[15];

    int N = in_sizes[0] / 32;
    int E = in_sizes[1] / 2;
    int Gn = out_size;  // 4096
    const int* srcp = ei;
    const int* dstp = ei + E;

    char* p = (char*)d_ws;
    auto alloc = [&](size_t bytes) -> char* {
        char* r = p;
        p += (bytes + 255) & ~(size_t)255;
        return r;
    };
    f16* hA = (f16*)alloc((size_t)N * H96 * 2);
    f16* hB = (f16*)alloc((size_t)N * H96 * 2);
    f16* aggf = (f16*)alloc((size_t)N * H96 * 2);
    f16* wf16 = (f16*)alloc((size_t)184320 * 2);
    f16* wpt = (f16*)alloc((size_t)LAYERS * 27648 * 2);
    int nb = (N + SCAN_B - 1) / SCAN_B;
    int* deg = (int*)alloc((size_t)N * 4);
    int* incl = (int*)alloc((size_t)nb * SCAN_B * 4);
    int* bsum = (int*)alloc((size_t)nb * 4);
    int* rs = (int*)alloc((size_t)(N + 1) * 4);
    int* cur = (int*)alloc((size_t)N * 4);
    int* es = (int*)alloc((size_t)E * 4);
    int nb2 = (Gn + SCAN_B - 1) / SCAN_B;
    int* gdeg = (int*)alloc((size_t)Gn * 4);
    int* gincl = (int*)alloc((size_t)nb2 * SCAN_B * 4);
    int* gbsum = (int*)alloc((size_t)nb2 * 4);
    int* grs = (int*)alloc((size_t)(Gn + 1) * 4);
    f16* pooled = (f16*)alloc((size_t)Gn * H96 * 2);
    f16* h1 = (f16*)alloc((size_t)Gn * 384 * 2);
    f16* h2 = (f16*)alloc((size_t)Gn * H96 * 2);

    f16* convw16 = wf16;
    f16* wih16 = wf16 + 55296;
    f16* whh16 = wf16 + 82944;
    f16* fc1w16 = wf16 + 110592;
    f16* fc2w16 = wf16 + 147456;

    hipMemsetAsync(deg, 0, (size_t)N * 4, stream);
    hipMemsetAsync(gdeg, 0, (size_t)Gn * 4, stream);

    k_f2h<<<720, 256, 0, stream>>>(conv_w, wih, whh, fc1w, fc2w, wf16);
    k_wpt<<<dim3(5, 6), 256, 0, stream>>>(wih16, convw16, wpt);
    k_pad<<<(N * H96 + 255) / 256, 256, 0, stream>>>(x, hA, N);
    // edge CSR (by dst)
    k_hist<<<(E + 255) / 256, 256, 0, stream>>>(dstp, deg, E);
    k_scan1<<<nb, SCAN_B, 0, stream>>>(deg, incl, bsum, N);
    k_scan2<<<1, 64, 0, stream>>>(bsum, nb);
    k_scan3<<<(N + 255) / 256, 256, 0, stream>>>(deg, incl, bsum, rs, cur, N, E);
    k_fill<<<(E + 255) / 256, 256, 0, stream>>>(srcp, dstp, cur, es, E);
    // graph CSR (batch sorted)
    k_hist<<<(N + 255) / 256, 256, 0, stream>>>(batch, gdeg, N);
    k_scan1<<<nb2, SCAN_B, 0, stream>>>(gdeg, gincl, gbsum, Gn);
    k_scan2<<<1, 64, 0, stream>>>(gbsum, nb2);
    k_scan3<<<(Gn + 255) / 256, 256, 0, stream>>>(gdeg, gincl, gbsum, grs, (int*)nullptr, Gn, N);

    int nt16 = (N + 15) / 16;
    for (int l = 0; l < LAYERS; l++) {
        f16* hin = (l & 1) ? hB : hA;
        f16* hout = (l & 1) ? hA : hB;
        k_gather<<<nt16, 256, 0, stream>>>(hin, rs, es, aggf, N);
        k_gru<<<1280, 384, 0, stream>>>(aggf, hin, hout, wpt + (size_t)l * 27648, whh16, bih, bhh, N);
    }

    k_pool2<<<Gn, 128, 0, stream>>>(hA, grs, gamma, beta, pooled, Gn);
    k_mlp<3, 6, 384, true><<<dim3((Gn + 63) / 64, 4), 256, 0, stream>>>(pooled, fc1w16, fc1b, h1, Gn);
    k_mlp<12, 6, 96, true><<<dim3((Gn + 63) / 64, 1), 256, 0, stream>>>(h1, fc2w16, fc2b, h2, Gn);
    k_mlp3<<<(Gn + 255) / 256, 256, 0, stream>>>(h2, fc3w, fc3b, (float*)d_out, Gn);
}